// Round 8
// baseline (326.600 us; speedup 1.0000x reference)
//
#include <hip/hip_runtime.h>
#include <hip/hip_bf16.h>

// VectorQuantizer via MFMA. R8: R7 structure (E frags in regs, Z frags in LDS,
// scores in acc regs) with the occupancy cap removed (waves_per_eu(2,2) max-arg
// was silently pinning 1 block/CU since R5) and 2 row-batches per block to
// amortize E-frag build + en2. Numerics identical to R5-R7 (absmax 0.0):
// scores = en2 - 2*Z.E^T via bf16 hi/lo 3-product MFMA, EPS band, exact fp32
// reference rescore, u64 (dist_bits<<32|idx) atomicMin == strict-< ascending-k.
constexpr int NELEM = 8388608;            // 32*64*64*64
constexpr int ROWS  = 64;                 // rows per batch
constexpr int NBLK  = 131072 / 128;       // 1024 blocks, 128 rows each
constexpr int ZS    = 68;                 // z tile stride (dwords)
constexpr float EPS = 2e-4f;              // R5-R7-validated band
constexpr int QCAP  = 1024;               // candidate queue (~73 expected/batch)

typedef short bf16x8 __attribute__((ext_vector_type(8)));
typedef float v4f    __attribute__((ext_vector_type(4)));

// 8 consecutive fp32 -> bf16 hi + lo (lo = rne(x - hi)), scaled. Frozen since R5.
__device__ inline void cvt_hilo8(const float* __restrict__ s, float scale,
                                 bf16x8& hi, bf16x8& lo) {
#pragma unroll
    for (int j = 0; j < 8; ++j) {
        float x = scale * s[j];
        __hip_bfloat16 h = __float2bfloat16(x);
        float hf = __bfloat162float(h);
        __hip_bfloat16 l = __float2bfloat16(x - hf);
        hi[j] = (short)__bfloat16_as_ushort(h);
        lo[j] = (short)__bfloat16_as_ushort(l);
    }
}

// Exact reference rescore of (row,code) -> atomicMin key. Frozen since R5.
__device__ inline void exact_rescore(int row, int code,
                                     const float* s_zb, const float* s_en2,
                                     const float* s_zn2,
                                     unsigned long long* s_key,
                                     const float* __restrict__ emb) {
    const float* zr = s_zb + row * ZS;
    const float* er = emb + (size_t)code * 64;
    float a = 0.f, b = 0.f, c2 = 0.f, d = 0.f;
#pragma unroll
    for (int g = 0; g < 16; ++g) {
        a  += zr[4*g]   * er[4*g];   b  += zr[4*g+1] * er[4*g+1];
        c2 += zr[4*g+2] * er[4*g+2]; d  += zr[4*g+3] * er[4*g+3];
    }
    float dot  = (a + b) + (c2 + d);
    float dist = (s_zn2[row] + s_en2[code]) - 2.0f * dot;
    unsigned long long key =
        ((unsigned long long)__float_as_uint(dist) << 32) | (unsigned)code;
    atomicMin(&s_key[row], key);
}

// Block = 512 threads = 8 waves; 128 rows (2 batches of 64) x all 512 codes.
// Wave w owns code-tiles [4w,4w+4): E hi/lo fragments in registers, built once.
// launch_bounds(512,4): min 4 waves/EU -> VGPR cap 128, NO residency max ->
// 2 blocks/CU co-resident (the R5-R7 waves_per_eu max-arg pinned 1 block/CU).
// MFMA 16x16x32: A=-2E (m=code), B=Z (n=row), C: col=lane&15 (row),
// row=quad*4+reg (code) [m89 layout, R5-R7-validated].
__global__ __launch_bounds__(512, 4)
void vq_main(const float* __restrict__ z,
             const float* __restrict__ emb,
             float* __restrict__ out) {
    __shared__ float  s_z[ROWS * ZS];           // 17.4 KB exact z tile
    __shared__ bf16x8 s_zfrag[4][2][2][64];     // 16 KB  [rt][kc][hi/lo][lane]
    __shared__ float  s_en2[512];
    __shared__ float  s_zn2[ROWS];
    __shared__ float  s_wmin[8][ROWS];
    __shared__ float  s_thr[ROWS];
    __shared__ unsigned long long s_key[ROWS];
    __shared__ unsigned s_q[QCAP];              // (row<<16)|code
    __shared__ int s_qn;
    __shared__ float s_lpart[8];

    const int tid  = threadIdx.x;
    const int lane = tid & 63;
    const int wid  = __builtin_amdgcn_readfirstlane(tid >> 6);
    const int mcol = lane & 15;
    const int quad = lane >> 4;

    // ---- once per block: E fragments for this wave's 4 code-tiles ----
    bf16x8 eH[4][2], eL[4][2];
#pragma unroll
    for (int ct = 0; ct < 4; ++ct)
#pragma unroll
        for (int kc = 0; kc < 2; ++kc)
            cvt_hilo8(emb + (size_t)((wid * 4 + ct) * 16 + mcol) * 64 + kc * 32 + quad * 8,
                      -2.0f, eH[ct][kc], eL[ct][kc]);

    // ---- once per block: exact en2, 1 code/thread (reference quad-acc order) ----
    {
        const float4* e4 = (const float4*)(emb + (size_t)tid * 64);
        float a = 0.f, b = 0.f, cc = 0.f, d = 0.f;
#pragma unroll
        for (int i = 0; i < 16; ++i) {
            float4 v = e4[i];
            a += v.x * v.x; b += v.y * v.y; cc += v.z * v.z; d += v.w * v.w;
        }
        s_en2[tid] = (a + b) + (cc + d);
    }

    float ltot = 0.f;   // per-thread loss accumulator across batches

    for (int batch = 0; batch < 2; ++batch) {
        const int rowbase = blockIdx.x * 128 + batch * 64;
        __syncthreads();  // prior batch done with s_z/s_key; s_en2 visible (batch 0)

        // ---- stage z tile (coalesced, 8 floats/thread); init keys/queue ----
        {
            const int row = tid >> 3, seg = tid & 7;
            const float4* gp = (const float4*)(z + ((size_t)rowbase + row) * 64 + seg * 8);
            *(float4*)&s_z[row * ZS + seg * 8]     = gp[0];
            *(float4*)&s_z[row * ZS + seg * 8 + 4] = gp[1];
        }
        if (tid < ROWS) s_key[tid] = ~0ULL;
        if (tid == 0) s_qn = 0;
        __syncthreads();

        // ---- exact zn2 per row (reference order) ----
        if (tid < ROWS) {
            const float* zr = &s_z[tid * ZS];
            float a = 0.f, b = 0.f, c = 0.f, d = 0.f;
#pragma unroll
            for (int i = 0; i < 16; ++i) {
                a += zr[4*i]   * zr[4*i];   b += zr[4*i+1] * zr[4*i+1];
                c += zr[4*i+2] * zr[4*i+2]; d += zr[4*i+3] * zr[4*i+3];
            }
            s_zn2[tid] = (a + b) + (c + d);
        }
        // ---- Z B-fragments: one (rt,kc,lane) hi/lo pair per thread ----
        {
            const int fl = tid & 63, kc = (tid >> 6) & 1, rt = tid >> 7;
            const int row = rt * 16 + (fl & 15), koff = kc * 32 + (fl >> 4) * 8;
            bf16x8 hi, lo;
            cvt_hilo8(&s_z[row * ZS + koff], 1.0f, hi, lo);
            s_zfrag[rt][kc][0][fl] = hi;
            s_zfrag[rt][kc][1][fl] = lo;
        }
        __syncthreads();

        // ---- MFMA: acc[ct][rt] = en2 - 2*Z.E^T (chain order frozen since R6) ----
        v4f acc[4][4];
#pragma unroll
        for (int rt = 0; rt < 4; ++rt) {
            bf16x8 zH0 = s_zfrag[rt][0][0][lane], zL0 = s_zfrag[rt][0][1][lane];
            bf16x8 zH1 = s_zfrag[rt][1][0][lane], zL1 = s_zfrag[rt][1][1][lane];
#pragma unroll
            for (int ct = 0; ct < 4; ++ct) {
                v4f a = *(const v4f*)&s_en2[(wid * 4 + ct) * 16 + quad * 4];
                a = __builtin_amdgcn_mfma_f32_16x16x32_bf16(eH[ct][0], zH0, a, 0, 0, 0);
                a = __builtin_amdgcn_mfma_f32_16x16x32_bf16(eH[ct][0], zL0, a, 0, 0, 0);
                a = __builtin_amdgcn_mfma_f32_16x16x32_bf16(eL[ct][0], zH0, a, 0, 0, 0);
                a = __builtin_amdgcn_mfma_f32_16x16x32_bf16(eH[ct][1], zH1, a, 0, 0, 0);
                a = __builtin_amdgcn_mfma_f32_16x16x32_bf16(eH[ct][1], zL1, a, 0, 0, 0);
                a = __builtin_amdgcn_mfma_f32_16x16x32_bf16(eL[ct][1], zH1, a, 0, 0, 0);
                acc[ct][rt] = a;
            }
        }

        // ---- per-row min over this wave's 64 codes (quad shuffle merge) ----
#pragma unroll
        for (int rt = 0; rt < 4; ++rt) {
            float mn = 3.402823466e38f;
#pragma unroll
            for (int ct = 0; ct < 4; ++ct) {
                v4f a = acc[ct][rt];
                mn = fminf(mn, fminf(fminf(a.x, a.y), fminf(a.z, a.w)));
            }
            mn = fminf(mn, __shfl_xor(mn, 16, 64));
            mn = fminf(mn, __shfl_xor(mn, 32, 64));
            if (quad == 0) s_wmin[wid][rt * 16 + mcol] = mn;
        }
        __syncthreads();
        if (tid < ROWS) {
            float m = s_wmin[0][tid];
#pragma unroll
            for (int w = 1; w < 8; ++w) m = fminf(m, s_wmin[w][tid]);
            s_thr[tid] = m + EPS;
        }
        __syncthreads();

        // ---- band scan over register scores -> candidate queue ----
#pragma unroll
        for (int rt = 0; rt < 4; ++rt) {
            const int row = rt * 16 + mcol;
            const float thr = s_thr[row];
#pragma unroll
            for (int ct = 0; ct < 4; ++ct) {
                v4f a = acc[ct][rt];
                float m4 = fminf(fminf(a.x, a.y), fminf(a.z, a.w));
                if (m4 <= thr) {
#pragma unroll
                    for (int r = 0; r < 4; ++r) {
                        if (a[r] <= thr) {
                            const int code = (wid * 4 + ct) * 16 + quad * 4 + r;
                            int slot = atomicAdd(&s_qn, 1);
                            if (slot < QCAP)
                                s_q[slot] = ((unsigned)row << 16) | (unsigned)code;
                            else  // overflow: rescore inline, nothing dropped
                                exact_rescore(row, code, s_z, s_en2, s_zn2, s_key, emb);
                        }
                    }
                }
            }
        }
        __syncthreads();

        // ---- exact reference rescore of queued candidates ----
        {
            const int qn = s_qn < QCAP ? s_qn : QCAP;
            for (int i = tid; i < qn; i += 512) {
                const unsigned e = s_q[i];
                exact_rescore((int)(e >> 16), (int)(e & 0xFFFF),
                              s_z, s_en2, s_zn2, s_key, emb);
            }
        }
        __syncthreads();

        // ---- epilogue: quantized_st, indices, loss (8 threads/row, 8 floats) ----
        {
            const int row = tid >> 3, seg = tid & 7;
            const int widx = (int)(unsigned)(s_key[row] & 0x1FFULL);
            const float* er = emb + (size_t)widx * 64 + seg * 8;
            const float* zr = &s_z[row * ZS + seg * 8];
            float* qo = out + 1 + ((size_t)rowbase + row) * 64 + seg * 8;
            float lsum = 0.f;
#pragma unroll
            for (int j = 0; j < 8; ++j) {
                float zv = zr[j], ev = er[j];
                float q = zv + (ev - zv);    // reference STE arithmetic
                float df = q - zv; lsum += df * df;
                qo[j] = q;
            }
            if (seg == 0)
                out[1 + NELEM + rowbase + row] = (float)widx;
            ltot += lsum;
        }
    }

    // ---- loss: one reduce + one atomic per block ----
#pragma unroll
    for (int off = 32; off; off >>= 1) ltot += __shfl_down(ltot, off, 64);
    if (lane == 0) s_lpart[wid] = ltot;
    __syncthreads();
    if (tid == 0) {
        float p = 0.f;
#pragma unroll
        for (int w = 0; w < 8; ++w) p += s_lpart[w];
        atomicAdd(out, p * (1.25f / 8388608.0f));   // recon + 0.25*commit
    }
}

extern "C" void kernel_launch(void* const* d_in, const int* in_sizes, int n_in,
                              void* d_out, int out_size, void* d_ws, size_t ws_size,
                              hipStream_t stream) {
    const float* z   = (const float*)d_in[0];
    const float* emb = (const float*)d_in[1];
    float* out = (float*)d_out;

    hipMemsetAsync(out, 0, 4, stream);  // zero loss accumulator (capture-safe)
    vq_main<<<NBLK, 512, 0, stream>>>(z, emb, out);
}

// Round 9
// 203.249 us; speedup vs baseline: 1.6069x; 1.6069x over previous
//
#include <hip/hip_runtime.h>
#include <hip/hip_bf16.h>

// VectorQuantizer via MFMA. R9: R7 structure minus score retention — two-pass
// (pass1 min, pass2 bit-identical recompute + band scan) so total regs fit the
// 128 cap and TWO blocks/CU co-reside. Occupancy lessons: waves_per_eu(a,b)'s
// b is a MAX (pinned 1 blk/CU in R5-R7); __launch_bounds__ arg2 here is CUDA
// min-BLOCKS/CU semantics (R8: arg=4 -> 64-reg cap -> 550 MB spill).
// Numerics identical to R5-R8 (absmax 0.0): scores = en2 - 2*Z.E^T via bf16
// hi/lo 3-product MFMA, EPS band, exact fp32 reference rescore,
// u64 (dist_bits<<32|idx) atomicMin == strict-< ascending-k tie-break.
constexpr int NELEM = 8388608;            // 32*64*64*64
constexpr int ROWS  = 64;                 // rows per block
constexpr int NBLK  = 131072 / ROWS;      // 2048
constexpr int ZS    = 68;                 // z tile stride (dwords)
constexpr float EPS = 2e-4f;              // R5-R8-validated band
constexpr int QCAP  = 1024;               // candidate queue (~73 expected)

typedef short bf16x8 __attribute__((ext_vector_type(8)));
typedef float v4f    __attribute__((ext_vector_type(4)));

// 8 consecutive fp32 -> bf16 hi + lo (lo = rne(x - hi)), scaled. Frozen since R5.
__device__ inline void cvt_hilo8(const float* __restrict__ s, float scale,
                                 bf16x8& hi, bf16x8& lo) {
#pragma unroll
    for (int j = 0; j < 8; ++j) {
        float x = scale * s[j];
        __hip_bfloat16 h = __float2bfloat16(x);
        float hf = __bfloat162float(h);
        __hip_bfloat16 l = __float2bfloat16(x - hf);
        hi[j] = (short)__bfloat16_as_ushort(h);
        lo[j] = (short)__bfloat16_as_ushort(l);
    }
}

// Exact reference rescore of (row,code) -> atomicMin key. Frozen since R5.
__device__ inline void exact_rescore(int row, int code,
                                     const float* s_zb, const float* s_en2,
                                     const float* s_zn2,
                                     unsigned long long* s_key,
                                     const float* __restrict__ emb) {
    const float* zr = s_zb + row * ZS;
    const float* er = emb + (size_t)code * 64;
    float a = 0.f, b = 0.f, c2 = 0.f, d = 0.f;
#pragma unroll
    for (int g = 0; g < 16; ++g) {
        a  += zr[4*g]   * er[4*g];   b  += zr[4*g+1] * er[4*g+1];
        c2 += zr[4*g+2] * er[4*g+2]; d  += zr[4*g+3] * er[4*g+3];
    }
    float dot  = (a + b) + (c2 + d);
    float dist = (s_zn2[row] + s_en2[code]) - 2.0f * dot;
    unsigned long long key =
        ((unsigned long long)__float_as_uint(dist) << 32) | (unsigned)code;
    atomicMin(&s_key[row], key);
}

// One score tile: 6-MFMA chain, order frozen since R6. Deterministic ->
// pass1 and pass2 results are bit-identical for identical fragments.
__device__ inline v4f score_tile(v4f a,
                                 const bf16x8& eH0, const bf16x8& eL0,
                                 const bf16x8& eH1, const bf16x8& eL1,
                                 const bf16x8& zH0, const bf16x8& zL0,
                                 const bf16x8& zH1, const bf16x8& zL1) {
    a = __builtin_amdgcn_mfma_f32_16x16x32_bf16(eH0, zH0, a, 0, 0, 0);
    a = __builtin_amdgcn_mfma_f32_16x16x32_bf16(eH0, zL0, a, 0, 0, 0);
    a = __builtin_amdgcn_mfma_f32_16x16x32_bf16(eL0, zH0, a, 0, 0, 0);
    a = __builtin_amdgcn_mfma_f32_16x16x32_bf16(eH1, zH1, a, 0, 0, 0);
    a = __builtin_amdgcn_mfma_f32_16x16x32_bf16(eH1, zL1, a, 0, 0, 0);
    a = __builtin_amdgcn_mfma_f32_16x16x32_bf16(eL1, zH1, a, 0, 0, 0);
    return a;
}

// Block = 512 threads = 8 waves, 64 rows x all 512 codes.
// Wave w owns code-tiles [4w,4w+4): E hi/lo fragments in registers, built once.
// MFMA 16x16x32: A=-2E (m=code), B=Z (n=row), C: col=lane&15 (row),
// row=quad*4+reg (code) [m89 layout, R5-R8-validated].
__global__ __launch_bounds__(512, 2)
void vq_main(const float* __restrict__ z,
             const float* __restrict__ emb,
             float* __restrict__ out) {
    __shared__ float  s_z[ROWS * ZS];           // 17.4 KB exact z tile
    __shared__ bf16x8 s_zfrag[4][2][2][64];     // 16 KB [rt][kc][hi/lo][lane]
    __shared__ float  s_en2[512];
    __shared__ float  s_zn2[ROWS];
    __shared__ float  s_wmin[8][ROWS];
    __shared__ float  s_thr[ROWS];
    __shared__ unsigned long long s_key[ROWS];
    __shared__ unsigned s_q[QCAP];              // (row<<16)|code
    __shared__ int s_qn;
    __shared__ float s_lpart[8];

    const int tid  = threadIdx.x;
    const int lane = tid & 63;
    const int wid  = __builtin_amdgcn_readfirstlane(tid >> 6);
    const int mcol = lane & 15;
    const int quad = lane >> 4;

    // ---- E fragments for this wave's 4 code-tiles: built once, in registers ----
    bf16x8 eH[4][2], eL[4][2];
#pragma unroll
    for (int ct = 0; ct < 4; ++ct)
#pragma unroll
        for (int kc = 0; kc < 2; ++kc)
            cvt_hilo8(emb + (size_t)((wid * 4 + ct) * 16 + mcol) * 64 + kc * 32 + quad * 8,
                      -2.0f, eH[ct][kc], eL[ct][kc]);

    // ---- stage z tile (coalesced, 8 floats/thread) ----
    {
        const int row = tid >> 3, seg = tid & 7;
        const float4* gp = (const float4*)(z + ((size_t)blockIdx.x * ROWS + row) * 64 + seg * 8);
        *(float4*)&s_z[row * ZS + seg * 8]     = gp[0];
        *(float4*)&s_z[row * ZS + seg * 8 + 4] = gp[1];
    }
    // ---- exact en2, 1 code/thread (reference quad-accumulator order) ----
    {
        const float4* e4 = (const float4*)(emb + (size_t)tid * 64);
        float a = 0.f, b = 0.f, cc = 0.f, d = 0.f;
#pragma unroll
        for (int i = 0; i < 16; ++i) {
            float4 v = e4[i];
            a += v.x * v.x; b += v.y * v.y; cc += v.z * v.z; d += v.w * v.w;
        }
        s_en2[tid] = (a + b) + (cc + d);
    }
    if (tid < ROWS) s_key[tid] = ~0ULL;
    if (tid == 0) s_qn = 0;
    __syncthreads();

    // ---- exact zn2 per row ----
    if (tid < ROWS) {
        const float* zr = &s_z[tid * ZS];
        float a = 0.f, b = 0.f, c = 0.f, d = 0.f;
#pragma unroll
        for (int i = 0; i < 16; ++i) {
            a += zr[4*i]   * zr[4*i];   b += zr[4*i+1] * zr[4*i+1];
            c += zr[4*i+2] * zr[4*i+2]; d += zr[4*i+3] * zr[4*i+3];
        }
        s_zn2[tid] = (a + b) + (c + d);
    }
    // ---- Z B-fragments: one (rt,kc,lane) hi/lo pair per thread ----
    {
        const int fl = tid & 63, kc = (tid >> 6) & 1, rt = tid >> 7;
        const int row = rt * 16 + (fl & 15), koff = kc * 32 + (fl >> 4) * 8;
        bf16x8 hi, lo;
        cvt_hilo8(&s_z[row * ZS + koff], 1.0f, hi, lo);
        s_zfrag[rt][kc][0][fl] = hi;
        s_zfrag[rt][kc][1][fl] = lo;
    }
    __syncthreads();

    // ---- pass 1: compute scores, fold into per-row min (acc transient) ----
#pragma unroll
    for (int rt = 0; rt < 4; ++rt) {
        bf16x8 zH0 = s_zfrag[rt][0][0][lane], zL0 = s_zfrag[rt][0][1][lane];
        bf16x8 zH1 = s_zfrag[rt][1][0][lane], zL1 = s_zfrag[rt][1][1][lane];
        float mn = 3.402823466e38f;
#pragma unroll
        for (int ct = 0; ct < 4; ++ct) {
            v4f a = *(const v4f*)&s_en2[(wid * 4 + ct) * 16 + quad * 4];
            a = score_tile(a, eH[ct][0], eL[ct][0], eH[ct][1], eL[ct][1],
                           zH0, zL0, zH1, zL1);
            mn = fminf(mn, fminf(fminf(a.x, a.y), fminf(a.z, a.w)));
        }
        mn = fminf(mn, __shfl_xor(mn, 16, 64));
        mn = fminf(mn, __shfl_xor(mn, 32, 64));
        if (quad == 0) s_wmin[wid][rt * 16 + mcol] = mn;
    }
    __syncthreads();
    if (tid < ROWS) {
        float m = s_wmin[0][tid];
#pragma unroll
        for (int w = 1; w < 8; ++w) m = fminf(m, s_wmin[w][tid]);
        s_thr[tid] = m + EPS;
    }
    __syncthreads();

    // ---- pass 2: recompute (bit-identical), band scan -> candidate queue ----
#pragma unroll
    for (int rt = 0; rt < 4; ++rt) {
        bf16x8 zH0 = s_zfrag[rt][0][0][lane], zL0 = s_zfrag[rt][0][1][lane];
        bf16x8 zH1 = s_zfrag[rt][1][0][lane], zL1 = s_zfrag[rt][1][1][lane];
        const int row = rt * 16 + mcol;
        const float thr = s_thr[row];
#pragma unroll
        for (int ct = 0; ct < 4; ++ct) {
            v4f a = *(const v4f*)&s_en2[(wid * 4 + ct) * 16 + quad * 4];
            a = score_tile(a, eH[ct][0], eL[ct][0], eH[ct][1], eL[ct][1],
                           zH0, zL0, zH1, zL1);
            float m4 = fminf(fminf(a.x, a.y), fminf(a.z, a.w));
            if (m4 <= thr) {
#pragma unroll
                for (int r = 0; r < 4; ++r) {
                    if (a[r] <= thr) {
                        const int code = (wid * 4 + ct) * 16 + quad * 4 + r;
                        int slot = atomicAdd(&s_qn, 1);
                        if (slot < QCAP)
                            s_q[slot] = ((unsigned)row << 16) | (unsigned)code;
                        else  // overflow: rescore inline, nothing dropped
                            exact_rescore(row, code, s_z, s_en2, s_zn2, s_key, emb);
                    }
                }
            }
        }
    }
    __syncthreads();

    // ---- exact reference rescore of queued candidates ----
    {
        const int qn = s_qn < QCAP ? s_qn : QCAP;
        for (int i = tid; i < qn; i += 512) {
            const unsigned e = s_q[i];
            exact_rescore((int)(e >> 16), (int)(e & 0xFFFF),
                          s_z, s_en2, s_zn2, s_key, emb);
        }
    }
    __syncthreads();

    // ---- epilogue: quantized_st, indices, loss (8 threads/row, 8 floats) ----
    const int row = tid >> 3, seg = tid & 7;
    const int widx = (int)(unsigned)(s_key[row] & 0x1FFULL);
    const float* er = emb + (size_t)widx * 64 + seg * 8;
    const float* zr = &s_z[row * ZS + seg * 8];
    float* qo = out + 1 + ((size_t)blockIdx.x * ROWS + row) * 64 + seg * 8;
    float lsum = 0.f;
#pragma unroll
    for (int j = 0; j < 8; ++j) {
        float zv = zr[j], ev = er[j];
        float q = zv + (ev - zv);    // reference STE arithmetic
        float df = q - zv; lsum += df * df;
        qo[j] = q;
    }
    if (seg == 0)
        out[1 + NELEM + blockIdx.x * ROWS + row] = (float)widx;

#pragma unroll
    for (int off = 32; off; off >>= 1) lsum += __shfl_down(lsum, off, 64);
    if (lane == 0) s_lpart[wid] = lsum;
    __syncthreads();
    if (tid == 0) {
        float p = 0.f;
#pragma unroll
        for (int w = 0; w < 8; ++w) p += s_lpart[w];
        atomicAdd(out, p * (1.25f / 8388608.0f));   // recon + 0.25*commit
    }
}

extern "C" void kernel_launch(void* const* d_in, const int* in_sizes, int n_in,
                              void* d_out, int out_size, void* d_ws, size_t ws_size,
                              hipStream_t stream) {
    const float* z   = (const float*)d_in[0];
    const float* emb = (const float*)d_in[1];
    float* out = (float*)d_out;

    hipMemsetAsync(out, 0, 4, stream);  // zero loss accumulator (capture-safe)
    vq_main<<<NBLK, 512, 0, stream>>>(z, emb, out);
}

// Round 10
// 174.222 us; speedup vs baseline: 1.8746x; 1.1666x over previous
//
#include <hip/hip_runtime.h>
#include <hip/hip_bf16.h>

// VectorQuantizer via MFMA. R10: R9 two-pass structure + (1) all emb-derived
// setup (exact en2, bf16 hi/lo E-fragments) hoisted to a one-time prep kernel
// writing __device__ globals — R9 spent ~75% of its cycles redoing these as
// uncoalesced per-block L2 storms; (2) 4 row-batches per block (grid 512) to
// amortize the coalesced E-frag reload. Numerics identical to R5-R9 (absmax
// 0.0): scores = en2 - 2*Z.E^T via bf16 hi/lo 3-product MFMA (bit-identical
// fragments), EPS band, exact fp32 reference rescore, u64 (dist<<32|idx)
// atomicMin == strict-< ascending-k tie-break.
constexpr int NELEM = 8388608;            // 32*64*64*64
constexpr int ROWS  = 64;                 // rows per batch
constexpr int NBATCH= 4;                  // batches per block
constexpr int NBLK  = 131072 / (ROWS * NBATCH);  // 512 blocks
constexpr int ZS    = 68;                 // z tile stride (dwords)
constexpr float EPS = 2e-4f;              // R5-R9-validated band
constexpr int QCAP  = 1024;               // candidate queue (~73 expected/batch)

typedef short bf16x8 __attribute__((ext_vector_type(8)));
typedef float v4f    __attribute__((ext_vector_type(4)));

// Prep-kernel outputs (device globals: ws_size-independent, graph-capture-safe
// — R6-validated pattern). efrag: [wid][ct][kc][hi/lo][lane], 131 KB.
__device__ bf16x8 g_efrag[8][4][2][2][64];
__device__ float  g_en2[512];

// 8 consecutive fp32 -> bf16 hi + lo (lo = rne(x - hi)), scaled. Frozen since R5.
__device__ inline void cvt_hilo8(const float* __restrict__ s, float scale,
                                 bf16x8& hi, bf16x8& lo) {
#pragma unroll
    for (int j = 0; j < 8; ++j) {
        float x = scale * s[j];
        __hip_bfloat16 h = __float2bfloat16(x);
        float hf = __bfloat162float(h);
        __hip_bfloat16 l = __float2bfloat16(x - hf);
        hi[j] = (short)__bfloat16_as_ushort(h);
        lo[j] = (short)__bfloat16_as_ushort(l);
    }
}

// One-time: E fragments (A-layout, -2 scale) + exact en2 (reference quad-acc).
__global__ void __launch_bounds__(512) vq_prep(const float* __restrict__ emb) {
    const int g    = blockIdx.x * 512 + threadIdx.x;   // 4096 = 8wid*4ct*2kc*64lane
    const int lane = g & 63;
    const int kc   = (g >> 6) & 1;
    const int ct   = (g >> 7) & 3;
    const int wid  = g >> 9;
    const int code = (wid * 4 + ct) * 16 + (lane & 15);
    const int koff = kc * 32 + (lane >> 4) * 8;
    bf16x8 hi, lo;
    cvt_hilo8(emb + (size_t)code * 64 + koff, -2.0f, hi, lo);
    g_efrag[wid][ct][kc][0][lane] = hi;
    g_efrag[wid][ct][kc][1][lane] = lo;

    if (g < 512) {  // exact en2, one code/thread
        const float4* e4 = (const float4*)(emb + (size_t)g * 64);
        float a = 0.f, b = 0.f, cc = 0.f, d = 0.f;
#pragma unroll
        for (int i = 0; i < 16; ++i) {
            float4 v = e4[i];
            a += v.x * v.x; b += v.y * v.y; cc += v.z * v.z; d += v.w * v.w;
        }
        g_en2[g] = (a + b) + (cc + d);
    }
}

// Exact reference rescore of (row,code) -> atomicMin key. Frozen since R5.
__device__ inline void exact_rescore(int row, int code,
                                     const float* s_zb, const float* s_en2,
                                     const float* s_zn2,
                                     unsigned long long* s_key,
                                     const float* __restrict__ emb) {
    const float* zr = s_zb + row * ZS;
    const float* er = emb + (size_t)code * 64;
    float a = 0.f, b = 0.f, c2 = 0.f, d = 0.f;
#pragma unroll
    for (int g = 0; g < 16; ++g) {
        a  += zr[4*g]   * er[4*g];   b  += zr[4*g+1] * er[4*g+1];
        c2 += zr[4*g+2] * er[4*g+2]; d  += zr[4*g+3] * er[4*g+3];
    }
    float dot  = (a + b) + (c2 + d);
    float dist = (s_zn2[row] + s_en2[code]) - 2.0f * dot;
    unsigned long long key =
        ((unsigned long long)__float_as_uint(dist) << 32) | (unsigned)code;
    atomicMin(&s_key[row], key);
}

// One score tile: 6-MFMA chain, order frozen since R6 (deterministic ->
// pass1/pass2 bit-identical).
__device__ inline v4f score_tile(v4f a,
                                 const bf16x8& eH0, const bf16x8& eL0,
                                 const bf16x8& eH1, const bf16x8& eL1,
                                 const bf16x8& zH0, const bf16x8& zL0,
                                 const bf16x8& zH1, const bf16x8& zL1) {
    a = __builtin_amdgcn_mfma_f32_16x16x32_bf16(eH0, zH0, a, 0, 0, 0);
    a = __builtin_amdgcn_mfma_f32_16x16x32_bf16(eH0, zL0, a, 0, 0, 0);
    a = __builtin_amdgcn_mfma_f32_16x16x32_bf16(eL0, zH0, a, 0, 0, 0);
    a = __builtin_amdgcn_mfma_f32_16x16x32_bf16(eH1, zH1, a, 0, 0, 0);
    a = __builtin_amdgcn_mfma_f32_16x16x32_bf16(eH1, zL1, a, 0, 0, 0);
    a = __builtin_amdgcn_mfma_f32_16x16x32_bf16(eL1, zH1, a, 0, 0, 0);
    return a;
}

// Block = 512 threads = 8 waves; 256 rows (4 batches of 64) x all 512 codes.
// Wave w owns code-tiles [4w,4w+4): E frags loaded coalesced from g_efrag once.
// launch_bounds(512,2): CUDA min-blocks semantics -> 128-reg cap, no spill (R9).
// MFMA 16x16x32: A=-2E (m=code), B=Z (n=row), C: col=lane&15 (row),
// row=quad*4+reg (code) [m89 layout, R5-R9-validated].
__global__ __launch_bounds__(512, 2)
void vq_main(const float* __restrict__ z,
             const float* __restrict__ emb,
             float* __restrict__ out) {
    __shared__ float  s_z[ROWS * ZS];           // 17.4 KB exact z tile
    __shared__ bf16x8 s_zfrag[4][2][2][64];     // 16 KB [rt][kc][hi/lo][lane]
    __shared__ float  s_en2[512];
    __shared__ float  s_zn2[ROWS];
    __shared__ float  s_wmin[8][ROWS];
    __shared__ float  s_thr[ROWS];
    __shared__ unsigned long long s_key[ROWS];
    __shared__ unsigned s_q[QCAP];              // (row<<16)|code
    __shared__ int s_qn;
    __shared__ float s_lpart[8];

    const int tid  = threadIdx.x;
    const int lane = tid & 63;
    const int wid  = __builtin_amdgcn_readfirstlane(tid >> 6);
    const int mcol = lane & 15;
    const int quad = lane >> 4;

    // ---- once per block: E fragments (coalesced 16B/lane) + s_en2 ----
    bf16x8 eH[4][2], eL[4][2];
#pragma unroll
    for (int ct = 0; ct < 4; ++ct)
#pragma unroll
        for (int kc = 0; kc < 2; ++kc) {
            eH[ct][kc] = g_efrag[wid][ct][kc][0][lane];
            eL[ct][kc] = g_efrag[wid][ct][kc][1][lane];
        }
    if (tid < 512) s_en2[tid] = g_en2[tid];

    float ltot = 0.f;

    for (int batch = 0; batch < NBATCH; ++batch) {
        const int rowbase = blockIdx.x * (ROWS * NBATCH) + batch * ROWS;
        __syncthreads();  // prior batch done with s_z/s_key; s_en2 visible

        // ---- stage z tile (coalesced, 8 floats/thread); init keys/queue ----
        {
            const int row = tid >> 3, seg = tid & 7;
            const float4* gp = (const float4*)(z + ((size_t)rowbase + row) * 64 + seg * 8);
            *(float4*)&s_z[row * ZS + seg * 8]     = gp[0];
            *(float4*)&s_z[row * ZS + seg * 8 + 4] = gp[1];
        }
        if (tid < ROWS) s_key[tid] = ~0ULL;
        if (tid == 0) s_qn = 0;
        __syncthreads();

        // ---- exact zn2 per row (reference order) + Z B-fragments ----
        if (tid < ROWS) {
            const float* zr = &s_z[tid * ZS];
            float a = 0.f, b = 0.f, c = 0.f, d = 0.f;
#pragma unroll
            for (int i = 0; i < 16; ++i) {
                a += zr[4*i]   * zr[4*i];   b += zr[4*i+1] * zr[4*i+1];
                c += zr[4*i+2] * zr[4*i+2]; d += zr[4*i+3] * zr[4*i+3];
            }
            s_zn2[tid] = (a + b) + (c + d);
        }
        {
            const int fl = tid & 63, kc = (tid >> 6) & 1, rt = tid >> 7;
            const int row = rt * 16 + (fl & 15), koff = kc * 32 + (fl >> 4) * 8;
            bf16x8 hi, lo;
            cvt_hilo8(&s_z[row * ZS + koff], 1.0f, hi, lo);
            s_zfrag[rt][kc][0][fl] = hi;
            s_zfrag[rt][kc][1][fl] = lo;
        }
        __syncthreads();

        // ---- pass 1: scores -> per-row min (acc transient) ----
#pragma unroll
        for (int rt = 0; rt < 4; ++rt) {
            bf16x8 zH0 = s_zfrag[rt][0][0][lane], zL0 = s_zfrag[rt][0][1][lane];
            bf16x8 zH1 = s_zfrag[rt][1][0][lane], zL1 = s_zfrag[rt][1][1][lane];
            float mn = 3.402823466e38f;
#pragma unroll
            for (int ct = 0; ct < 4; ++ct) {
                v4f a = *(const v4f*)&s_en2[(wid * 4 + ct) * 16 + quad * 4];
                a = score_tile(a, eH[ct][0], eL[ct][0], eH[ct][1], eL[ct][1],
                               zH0, zL0, zH1, zL1);
                mn = fminf(mn, fminf(fminf(a.x, a.y), fminf(a.z, a.w)));
            }
            mn = fminf(mn, __shfl_xor(mn, 16, 64));
            mn = fminf(mn, __shfl_xor(mn, 32, 64));
            if (quad == 0) s_wmin[wid][rt * 16 + mcol] = mn;
        }
        __syncthreads();
        if (tid < ROWS) {
            float m = s_wmin[0][tid];
#pragma unroll
            for (int w = 1; w < 8; ++w) m = fminf(m, s_wmin[w][tid]);
            s_thr[tid] = m + EPS;
        }
        __syncthreads();

        // ---- pass 2: bit-identical recompute, band scan -> queue ----
#pragma unroll
        for (int rt = 0; rt < 4; ++rt) {
            bf16x8 zH0 = s_zfrag[rt][0][0][lane], zL0 = s_zfrag[rt][0][1][lane];
            bf16x8 zH1 = s_zfrag[rt][1][0][lane], zL1 = s_zfrag[rt][1][1][lane];
            const int row = rt * 16 + mcol;
            const float thr = s_thr[row];
#pragma unroll
            for (int ct = 0; ct < 4; ++ct) {
                v4f a = *(const v4f*)&s_en2[(wid * 4 + ct) * 16 + quad * 4];
                a = score_tile(a, eH[ct][0], eL[ct][0], eH[ct][1], eL[ct][1],
                               zH0, zL0, zH1, zL1);
                float m4 = fminf(fminf(a.x, a.y), fminf(a.z, a.w));
                if (m4 <= thr) {
#pragma unroll
                    for (int r = 0; r < 4; ++r) {
                        if (a[r] <= thr) {
                            const int code = (wid * 4 + ct) * 16 + quad * 4 + r;
                            int slot = atomicAdd(&s_qn, 1);
                            if (slot < QCAP)
                                s_q[slot] = ((unsigned)row << 16) | (unsigned)code;
                            else  // overflow: rescore inline, nothing dropped
                                exact_rescore(row, code, s_z, s_en2, s_zn2, s_key, emb);
                        }
                    }
                }
            }
        }
        __syncthreads();

        // ---- exact reference rescore of queued candidates ----
        {
            const int qn = s_qn < QCAP ? s_qn : QCAP;
            for (int i = tid; i < qn; i += 512) {
                const unsigned e = s_q[i];
                exact_rescore((int)(e >> 16), (int)(e & 0xFFFF),
                              s_z, s_en2, s_zn2, s_key, emb);
            }
        }
        __syncthreads();

        // ---- epilogue: quantized_st, indices, loss (8 threads/row) ----
        {
            const int row = tid >> 3, seg = tid & 7;
            const int widx = (int)(unsigned)(s_key[row] & 0x1FFULL);
            const float* er = emb + (size_t)widx * 64 + seg * 8;
            const float* zr = &s_z[row * ZS + seg * 8];
            float* qo = out + 1 + ((size_t)rowbase + row) * 64 + seg * 8;
            float lsum = 0.f;
#pragma unroll
            for (int j = 0; j < 8; ++j) {
                float zv = zr[j], ev = er[j];
                float q = zv + (ev - zv);    // reference STE arithmetic
                float df = q - zv; lsum += df * df;
                qo[j] = q;
            }
            if (seg == 0)
                out[1 + NELEM + rowbase + row] = (float)widx;
            ltot += lsum;
        }
    }

    // ---- loss: one reduce + one atomic per block ----
#pragma unroll
    for (int off = 32; off; off >>= 1) ltot += __shfl_down(ltot, off, 64);
    if (lane == 0) s_lpart[wid] = ltot;
    __syncthreads();
    if (tid == 0) {
        float p = 0.f;
#pragma unroll
        for (int w = 0; w < 8; ++w) p += s_lpart[w];
        atomicAdd(out, p * (1.25f / 8388608.0f));   // recon + 0.25*commit
    }
}

extern "C" void kernel_launch(void* const* d_in, const int* in_sizes, int n_in,
                              void* d_out, int out_size, void* d_ws, size_t ws_size,
                              hipStream_t stream) {
    const float* z   = (const float*)d_in[0];
    const float* emb = (const float*)d_in[1];
    float* out = (float*)d_out;

    hipMemsetAsync(out, 0, 4, stream);  // zero loss accumulator (capture-safe)
    vq_prep<<<8, 512, 0, stream>>>(emb);
    vq_main<<<NBLK, 512, 0, stream>>>(z, emb, out);
}